// Round 11
// baseline (159.191 us; speedup 1.0000x reference)
//
#include <hip/hip_runtime.h>

typedef __attribute__((ext_vector_type(8))) short bf16x8;
typedef __attribute__((ext_vector_type(4))) float f32x4;

#define BTOT 32768
#define FDIM 128
#define TDIM 32
#define DDIM 16
#define HDIM 10
#define CDIM 320
#define ALPHA_C 0.1f
#define MARGIN_C 1.0f
#define SLOPE_C 0.2f
#define OFFSET_C 1.0e6f

// ws float offsets
#define WS_A0P  0           // 32 t x 16 o x 128 n bf16 = 65536 shorts
#define WS_MEAN 32768
#define WS_TC   33088
#define WS_CE   33152

__device__ __forceinline__ float leaky(float x) { return fmaxf(x, SLOPE_C * x); }

__device__ __forceinline__ unsigned short f2bf(float f) {   // RNE f32->bf16
    unsigned int u = __float_as_uint(f);
    u += 0x7fffu + ((u >> 16) & 1u);
    return (unsigned short)(u >> 16);
}

__device__ __forceinline__ f32x4 mfma32(bf16x8 a, bf16x8 b, f32x4 c) {
    return __builtin_amdgcn_mfma_f32_16x16x32_bf16(a, b, c, 0, 0, 0);
}

// leaky + pack 4 f32 -> 2 dwords of bf16 (RNE)
__device__ __forceinline__ void leaky_pack(f32x4 v, unsigned& p0, unsigned& p1) {
    float a0 = leaky(v[0]), a1 = leaky(v[1]), a2 = leaky(v[2]), a3 = leaky(v[3]);
    asm("v_cvt_pk_bf16_f32 %0, %1, %2" : "=v"(p0) : "v"(a0), "v"(a1));
    asm("v_cvt_pk_bf16_f32 %0, %1, %2" : "=v"(p1) : "v"(a2), "v"(a3));
}

// Lane (g,r16) holds act[k=g*4+r][j=r16] in p0 (k=g*4+0,1), p1 (k=g*4+2,3).
// B-frag for 16x16x32: elem jj of lane g = act[k=g*8+jj][j=r16] (zero for k>=16).
__device__ __forceinline__ bf16x8 build_bfrag(unsigned p0, unsigned p1, int g, int r16) {
    int s0 = ((2 * g) * 16 + r16) & 63;
    int s1 = ((2 * g + 1) * 16 + r16) & 63;
    unsigned w0 = (unsigned)__shfl((int)p0, s0, 64);
    unsigned w1 = (unsigned)__shfl((int)p1, s0, 64);
    unsigned w2 = (unsigned)__shfl((int)p0, s1, 64);
    unsigned w3 = (unsigned)__shfl((int)p1, s1, 64);
    unsigned zm = (g < 2) ? 0xFFFFFFFFu : 0u;   // k>=16 -> zero
    union { unsigned u[4]; bf16x8 v; } r;
    r.u[0] = w0 & zm; r.u[1] = w1 & zm; r.u[2] = w2 & zm; r.u[3] = w3 & zm;
    return r.v;
}

// a0p[t][o(16, zero-pad>=10)][n(128)] bf16 : per-t A-operand table, A[m=o][k=n]
__global__ void prep_kernel(const float* __restrict__ aw, const float* __restrict__ W0,
                            unsigned short* __restrict__ a0p) {
    int idx = blockIdx.x * blockDim.x + threadIdx.x;   // 65536
    if (idx >= 65536) return;
    int n = idx & 127, o = (idx >> 7) & 15, t = idx >> 11;
    unsigned short r = 0;
    if (o < 10) {
        const float* a = aw + ((size_t)t * FDIM + n) * DDIM;
        const float* w = W0 + o * DDIM;
        float s = 0.f;
#pragma unroll
        for (int d = 0; d < DDIM; ++d) s += a[d] * w[d];
        r = f2bf(s);
    }
    a0p[idx] = r;
}

// Full-MFMA pipeline. Grid 2048 = 1024 bchunk x 2 thalf; block 256 = 4 waves.
// Wave w: bsub = w>>1 (16 b's), tq = w&1 (8 t's): t = thalf*16 + tq*8 + tt.
__global__ __launch_bounds__(256, 8) void gemm0_fused(
    const float* __restrict__ X, const unsigned short* __restrict__ a0p,
    const float* __restrict__ W1, const float* __restrict__ W2,
    const float* __restrict__ W3, const float* __restrict__ Wh,
    const float* __restrict__ bh,
    float* __restrict__ rep, float* __restrict__ ce_acc,
    float* __restrict__ mean_acc)
{
    __shared__ unsigned short xs[32][136];
    __shared__ unsigned short w1x[16][32], w2x[16][32], w3x[16][32], whx[32][32];
    __shared__ float mred[2][16][12];

    int tid = threadIdx.x;
    int b0 = (blockIdx.x >> 1) * 32;
    int thalf = blockIdx.x & 1;

    // ---- stage X (32x128 f32 -> bf16), coalesced ----
#pragma unroll
    for (int k = 0; k < 4; ++k) {
        int idx = tid + k * 256;             // 1024 float4
        int row = idx >> 5, col4 = idx & 31;
        float4 v = reinterpret_cast<const float4*>(X + (size_t)(b0 + row) * FDIM)[col4];
        unsigned p0, p1;
        asm("v_cvt_pk_bf16_f32 %0, %1, %2" : "=v"(p0) : "v"(v.x), "v"(v.y));
        asm("v_cvt_pk_bf16_f32 %0, %1, %2" : "=v"(p1) : "v"(v.z), "v"(v.w));
        uint2 pk; pk.x = p0; pk.y = p1;
        *reinterpret_cast<uint2*>(&xs[row][col4 * 4]) = pk;
    }
    // ---- weight tables, zero-padded to k=32 ----
#pragma unroll
    for (int k = 0; k < 2; ++k) {
        int i = tid + k * 256;               // 512 = 16x32
        int o = i >> 5, kk = i & 31;
        bool in10 = (o < 10 && kk < 10);
        w1x[o][kk] = in10 ? f2bf(W1[o * 10 + kk]) : (unsigned short)0;
        w2x[o][kk] = in10 ? f2bf(W2[o * 10 + kk]) : (unsigned short)0;
        w3x[o][kk] = in10 ? f2bf(W3[o * 10 + kk]) : (unsigned short)0;
    }
#pragma unroll
    for (int k = 0; k < 4; ++k) {
        int i = tid + k * 256;               // 1024 = 32x32
        int o = i >> 5, kk = i & 31;
        whx[o][kk] = (kk < 10) ? f2bf(Wh[o * 10 + kk]) : (unsigned short)0;
    }
    __syncthreads();

    int lane = tid & 63, w = __builtin_amdgcn_readfirstlane(tid >> 6);
    int r16 = lane & 15, g = lane >> 4;
    int bsub = w >> 1, tq = w & 1;
    int bglob = b0 + bsub * 16 + r16;

    // B-operand X frags (j=b on r16), identical k-map as A (permutation-safe)
    bf16x8 xf[4];
#pragma unroll
    for (int s = 0; s < 4; ++s)
        xf[s] = *reinterpret_cast<const bf16x8*>(&xs[bsub * 16 + r16][s * 32 + g * 8]);

    // A-operand weight frags, loaded once
    bf16x8 w1f = *reinterpret_cast<const bf16x8*>(&w1x[r16][g * 8]);
    bf16x8 w2f = *reinterpret_cast<const bf16x8*>(&w2x[r16][g * 8]);
    bf16x8 w3f = *reinterpret_cast<const bf16x8*>(&w3x[r16][g * 8]);
    bf16x8 whAf = *reinterpret_cast<const bf16x8*>(&whx[r16][g * 8]);
    bf16x8 whBf = *reinterpret_cast<const bf16x8*>(&whx[16 + r16][g * 8]);
    f32x4 bhA, bhB;
#pragma unroll
    for (int r = 0; r < 4; ++r) { bhA[r] = bh[g * 4 + r]; bhB[r] = bh[16 + g * 4 + r]; }
    const f32x4 zero4 = {0.f, 0.f, 0.f, 0.f};

    float ce_local = 0.f;

    for (int tt2 = 0; tt2 < 2; ++tt2) {      // runtime outer, unrolled inner (rule #20)
#pragma unroll
        for (int q = 0; q < 4; ++q) {
            int tloc = tq * 8 + tt2 * 4 + q;           // 0..15 within half
            int t = thalf * 16 + tloc;
            // L0: D0[o][b], two independent accumulators to halve the dep chain
            const bf16x8* ap = reinterpret_cast<const bf16x8*>(
                a0p + ((size_t)t * 16 + r16) * 128);
            f32x4 accA = zero4, accB = zero4;
            accA = mfma32(ap[0 * 4 + g], xf[0], accA);
            accB = mfma32(ap[1 * 4 + g], xf[1], accB);
            accA = mfma32(ap[2 * 4 + g], xf[2], accA);
            accB = mfma32(ap[3 * 4 + g], xf[3], accB);
            f32x4 acc;
#pragma unroll
            for (int r = 0; r < 4; ++r) acc[r] = accA[r] + accB[r];

            unsigned p0, p1;
            leaky_pack(acc, p0, p1);
            bf16x8 bf = build_bfrag(p0, p1, g, r16);
            f32x4 d1 = mfma32(w1f, bf, zero4);
            leaky_pack(d1, p0, p1);
            bf = build_bfrag(p0, p1, g, r16);
            f32x4 d2 = mfma32(w2f, bf, zero4);
            leaky_pack(d2, p0, p1);
            bf = build_bfrag(p0, p1, g, r16);
            f32x4 d3 = mfma32(w3f, bf, zero4);   // rep[o=g*4+r][b=r16], o>=10 exact 0

            // rep store (own b row, 10 floats across g=0..2)
            float* rp = rep + (size_t)bglob * CDIM + t * HDIM + g * 4;
            if (g < 2) {
                float2 v0; v0.x = d3[0]; v0.y = d3[1];
                float2 v1; v1.x = d3[2]; v1.y = d3[3];
                reinterpret_cast<float2*>(rp)[0] = v0;
                reinterpret_cast<float2*>(rp)[1] = v1;
            } else if (g == 2) {
                float2 v0; v0.x = d3[0]; v0.y = d3[1];
                reinterpret_cast<float2*>(rp)[0] = v0;
            }

            // mean partial: butterfly over 16 b-lanes
            float m0 = d3[0], m1 = d3[1], m2 = d3[2], m3 = d3[3];
#pragma unroll
            for (int msk = 1; msk < 16; msk <<= 1) {
                m0 += __shfl_xor(m0, msk, 64);
                m1 += __shfl_xor(m1, msk, 64);
                m2 += __shfl_xor(m2, msk, 64);
                m3 += __shfl_xor(m3, msk, 64);
            }
            if (r16 == 0 && g < 3) {
                float4 mv; mv.x = m0; mv.y = m1; mv.z = m2; mv.w = m3;
                *reinterpret_cast<float4*>(&mred[bsub][tloc][g * 4]) = mv;
            }

            // head: pred[o][b] = Wh . leaky(rep) + bh  (2x 16x16x32)
            leaky_pack(d3, p0, p1);
            bf = build_bfrag(p0, p1, g, r16);
            f32x4 pA = mfma32(whAf, bf, bhA);
            f32x4 pB = mfma32(whBf, bf, bhB);

            // LSE over 32 classes (8 in-lane + butterfly over g)
            float mx = fmaxf(fmaxf(fmaxf(pA[0], pA[1]), fmaxf(pA[2], pA[3])),
                             fmaxf(fmaxf(pB[0], pB[1]), fmaxf(pB[2], pB[3])));
            mx = fmaxf(mx, __shfl_xor(mx, 16, 64));
            mx = fmaxf(mx, __shfl_xor(mx, 32, 64));
            float se = __expf(pA[0] - mx) + __expf(pA[1] - mx) +
                       __expf(pA[2] - mx) + __expf(pA[3] - mx) +
                       __expf(pB[0] - mx) + __expf(pB[1] - mx) +
                       __expf(pB[2] - mx) + __expf(pB[3] - mx);
            se += __shfl_xor(se, 16, 64);
            se += __shfl_xor(se, 32, 64);
            float lse = mx + __logf(se);
            // pt = pred[class=t][b=r16]: class local to half = tloc; holder lane
            // g' = tloc>>2 = tq*2 + tt2, reg = q; half picked by thalf.
            float pr = thalf ? pB[q] : pA[q];
            float ptv = __shfl(pr, (tq * 2 + tt2) * 16 + r16, 64);
            ce_local += lse - ptv;
        }
    }

    if (g == 0) atomicAdd(&ce_acc[bglob], ce_local);
    __syncthreads();
    for (int i = tid; i < 16 * HDIM; i += 256) {
        int tloc = i / 10, o = i - tloc * 10;
        atomicAdd(&mean_acc[(thalf * 16 + tloc) * HDIM + o],
                  mred[0][tloc][o] + mred[1][tloc][o]);
    }
}

// Triplet-center hinge: block = 32 b's staged in LDS, thread = (t, 4 b's).
__global__ __launch_bounds__(256) void tc_kernel(const float* __restrict__ rep,
    const float* __restrict__ mean_acc, float* __restrict__ tc_sum)
{
    __shared__ float tile[32][CDIM];     // 40 KB
    __shared__ float mm[CDIM];
    __shared__ float msq[TDIM];
    __shared__ float wpart[4];
    int tid = threadIdx.x;
    int b0 = blockIdx.x * 32;

    for (int i = tid; i < CDIM; i += 256) mm[i] = mean_acc[i] * (1.f / BTOT);
    const float4* src = reinterpret_cast<const float4*>(rep + (size_t)b0 * CDIM);
#pragma unroll
    for (int k = 0; k < 10; ++k) {       // 2560 float4, coalesced
        int idx = tid + k * 256;
        int row = idx / 80, col4 = idx - row * 80;
        *reinterpret_cast<float4*>(&tile[row][col4 * 4]) = src[idx];
    }
    __syncthreads();
    if (tid < TDIM) {
        float s = 0.f;
#pragma unroll
        for (int h = 0; h < HDIM; ++h) { float v = mm[tid * HDIM + h]; s += v * v; }
        msq[tid] = s;
    }
    __syncthreads();

    int t = tid & 31, bg = tid >> 5;
    float rv[4][HDIM], rsq[4];
#pragma unroll
    for (int j = 0; j < 4; ++j) {
        const float* rp = &tile[bg * 4 + j][t * HDIM];
        float s = 0.f;
#pragma unroll
        for (int q = 0; q < 5; ++q) {
            float2 v = reinterpret_cast<const float2*>(rp)[q];
            rv[j][2 * q] = v.x; rv[j][2 * q + 1] = v.y;
            s += v.x * v.x + v.y * v.y;
        }
        rsq[j] = s;
    }
    float pos[4], neg[4];
#pragma unroll
    for (int j = 0; j < 4; ++j) { pos[j] = 0.f; neg[j] = 1e30f; }
#pragma unroll 4
    for (int c = 0; c < TDIM; ++c) {
        float m0[HDIM];
#pragma unroll
        for (int q = 0; q < 5; ++q) {
            float2 v = reinterpret_cast<const float2*>(&mm[c * HDIM])[q];
            m0[2 * q] = v.x; m0[2 * q + 1] = v.y;
        }
        float mq = msq[c];
        bool isT = (c == t);
#pragma unroll
        for (int j = 0; j < 4; ++j) {
            float dot = 0.f;
#pragma unroll
            for (int h = 0; h < HDIM; ++h) dot += rv[j][h] * m0[h];
            float s = rsq[j] - 2.f * dot + mq;
            if (isT) pos[j] = s;
            float s2 = isT ? s + OFFSET_C : s;
            neg[j] = fminf(neg[j], s2);
        }
    }
    float hs = 0.f;
#pragma unroll
    for (int j = 0; j < 4; ++j) hs += fmaxf(pos[j] + MARGIN_C - neg[j], 0.f);
#pragma unroll
    for (int m = 1; m < 64; m <<= 1) hs += __shfl_xor(hs, m, 64);
    int lane = tid & 63, w = tid >> 6;
    if (lane == 0) wpart[w] = hs;
    __syncthreads();
    if (tid == 0) atomicAdd(tc_sum, wpart[0] + wpart[1] + wpart[2] + wpart[3]);
}

__global__ void final_kernel(const float* __restrict__ ce_acc,
                             const float* __restrict__ tc_sum, float* __restrict__ loss)
{
    int b = blockIdx.x * blockDim.x + threadIdx.x;
    if (b < BTOT)
        loss[b] = ALPHA_C * (tc_sum[0] * (1.f / ((float)BTOT * TDIM)))
                + ce_acc[b] * (1.f / TDIM);
}

extern "C" void kernel_launch(void* const* d_in, const int* in_sizes, int n_in,
                              void* d_out, int out_size, void* d_ws, size_t ws_size,
                              hipStream_t stream) {
    const float* X  = (const float*)d_in[0];
    const float* aw = (const float*)d_in[1];
    const float* W0 = (const float*)d_in[2];
    const float* W1 = (const float*)d_in[3];
    const float* W2 = (const float*)d_in[4];
    const float* W3 = (const float*)d_in[5];
    const float* Wh = (const float*)d_in[6];
    const float* bh = (const float*)d_in[7];
    float* ws = (float*)d_ws;
    unsigned short* a0p = (unsigned short*)(ws + WS_A0P);
    float* mean_acc = ws + WS_MEAN;
    float* tc_sum   = ws + WS_TC;
    float* ce_acc   = ws + WS_CE;
    float* out_rep = (float*)d_out;        // [32768][320]
    float* loss = out_rep + (size_t)BTOT * TDIM * HDIM;

    // zero mean_acc + tc pad + ce_acc
    hipMemsetAsync(mean_acc, 0, (384 + BTOT) * sizeof(float), stream);
    prep_kernel<<<256, 256, 0, stream>>>(aw, W0, a0p);
    gemm0_fused<<<2048, 256, 0, stream>>>(X, a0p, W1, W2, W3, Wh, bh,
                                          out_rep, ce_acc, mean_acc);
    tc_kernel<<<BTOT / 32, 256, 0, stream>>>(out_rep, mean_acc, tc_sum);
    final_kernel<<<BTOT / 256, 256, 0, stream>>>(ce_acc, tc_sum, loss);
}

// Round 12
// 99.730 us; speedup vs baseline: 1.5962x; 1.5962x over previous
//
#include <hip/hip_runtime.h>

typedef __attribute__((ext_vector_type(8))) short bf16x8;
typedef __attribute__((ext_vector_type(4))) float f32x4;

#define BTOT 32768
#define FDIM 128
#define TDIM 32
#define DDIM 16
#define HDIM 10
#define CDIM 320
#define ALPHA_C 0.1f
#define MARGIN_C 1.0f
#define SLOPE_C 0.2f
#define OFFSET_C 1.0e6f

// ws float offsets
#define WS_A0P  0           // 32 t x 16 o x 128 n bf16 = 65536 shorts
#define WS_MEAN 32768
#define WS_TC   33088
#define WS_CE   33152

__device__ __forceinline__ float leaky(float x) { return fmaxf(x, SLOPE_C * x); }

__device__ __forceinline__ unsigned short f2bf(float f) {   // RNE f32->bf16
    unsigned int u = __float_as_uint(f);
    u += 0x7fffu + ((u >> 16) & 1u);
    return (unsigned short)(u >> 16);
}

__device__ __forceinline__ f32x4 mfma32(bf16x8 a, bf16x8 b, f32x4 c) {
    return __builtin_amdgcn_mfma_f32_16x16x32_bf16(a, b, c, 0, 0, 0);
}

// leaky + pack 4 f32 -> 2 dwords of bf16 (RNE)
__device__ __forceinline__ void leaky_pack(f32x4 v, unsigned& p0, unsigned& p1) {
    float a0 = leaky(v[0]), a1 = leaky(v[1]), a2 = leaky(v[2]), a3 = leaky(v[3]);
    asm("v_cvt_pk_bf16_f32 %0, %1, %2" : "=v"(p0) : "v"(a0), "v"(a1));
    asm("v_cvt_pk_bf16_f32 %0, %1, %2" : "=v"(p1) : "v"(a2), "v"(a3));
}

// Lane (g,r16) holds act[k=g*4+r][j=r16] in p0 (k=g*4+0,1), p1 (k=g*4+2,3).
// B-frag for 16x16x32: elem jj of lane g = act[k=g*8+jj][j=r16] (zero for k>=16).
__device__ __forceinline__ bf16x8 build_bfrag(unsigned p0, unsigned p1, int g, int r16) {
    int s0 = ((2 * g) * 16 + r16) & 63;
    int s1 = ((2 * g + 1) * 16 + r16) & 63;
    unsigned w0 = (unsigned)__shfl((int)p0, s0, 64);
    unsigned w1 = (unsigned)__shfl((int)p1, s0, 64);
    unsigned w2 = (unsigned)__shfl((int)p0, s1, 64);
    unsigned w3 = (unsigned)__shfl((int)p1, s1, 64);
    unsigned zm = (g < 2) ? 0xFFFFFFFFu : 0u;   // k>=16 -> zero
    union { unsigned u[4]; bf16x8 v; } r;
    r.u[0] = w0 & zm; r.u[1] = w1 & zm; r.u[2] = w2 & zm; r.u[3] = w3 & zm;
    return r.v;
}

// a0p[t][o(16, zero-pad>=10)][n(128)] bf16 : per-t A-operand table, A[m=o][k=n]
__global__ void prep_kernel(const float* __restrict__ aw, const float* __restrict__ W0,
                            unsigned short* __restrict__ a0p) {
    int idx = blockIdx.x * blockDim.x + threadIdx.x;   // 65536
    if (idx >= 65536) return;
    int n = idx & 127, o = (idx >> 7) & 15, t = idx >> 11;
    unsigned short r = 0;
    if (o < 10) {
        const float* a = aw + ((size_t)t * FDIM + n) * DDIM;
        const float* w = W0 + o * DDIM;
        float s = 0.f;
#pragma unroll
        for (int d = 0; d < DDIM; ++d) s += a[d] * w[d];
        r = f2bf(s);
    }
    a0p[idx] = r;
}

// Full-MFMA pipeline. Grid 2048 = 1024 bchunk x 2 thalf; block 256 = 4 waves.
// Wave w: bsub = w>>1 (16 b's), tq = w&1 (8 t's): t = thalf*16 + tq*8 + tt.
// launch_bounds(256,4): compiler budget ~128 VGPR -> lands ~56, no spill;
// runtime occupancy is set by actual VGPR (56 <= 64 -> 8 blocks/CU possible).
__global__ __launch_bounds__(256, 4) void gemm0_fused(
    const float* __restrict__ X, const unsigned short* __restrict__ a0p,
    const float* __restrict__ W1, const float* __restrict__ W2,
    const float* __restrict__ W3, const float* __restrict__ Wh,
    const float* __restrict__ bh,
    float* __restrict__ rep, float* __restrict__ ce_acc,
    float* __restrict__ mean_acc)
{
    __shared__ unsigned short xs[32][136];
    __shared__ unsigned short w1x[16][32], w2x[16][32], w3x[16][32], whx[32][32];
    __shared__ float mred[2][16][12];

    int tid = threadIdx.x;
    int b0 = (blockIdx.x >> 1) * 32;
    int thalf = blockIdx.x & 1;

    // ---- stage X (32x128 f32 -> bf16), coalesced ----
#pragma unroll
    for (int k = 0; k < 4; ++k) {
        int idx = tid + k * 256;             // 1024 float4
        int row = idx >> 5, col4 = idx & 31;
        float4 v = reinterpret_cast<const float4*>(X + (size_t)(b0 + row) * FDIM)[col4];
        unsigned p0, p1;
        asm("v_cvt_pk_bf16_f32 %0, %1, %2" : "=v"(p0) : "v"(v.x), "v"(v.y));
        asm("v_cvt_pk_bf16_f32 %0, %1, %2" : "=v"(p1) : "v"(v.z), "v"(v.w));
        uint2 pk; pk.x = p0; pk.y = p1;
        *reinterpret_cast<uint2*>(&xs[row][col4 * 4]) = pk;
    }
    // ---- weight tables, zero-padded to k=32 ----
#pragma unroll
    for (int k = 0; k < 2; ++k) {
        int i = tid + k * 256;               // 512 = 16x32
        int o = i >> 5, kk = i & 31;
        bool in10 = (o < 10 && kk < 10);
        w1x[o][kk] = in10 ? f2bf(W1[o * 10 + kk]) : (unsigned short)0;
        w2x[o][kk] = in10 ? f2bf(W2[o * 10 + kk]) : (unsigned short)0;
        w3x[o][kk] = in10 ? f2bf(W3[o * 10 + kk]) : (unsigned short)0;
    }
#pragma unroll
    for (int k = 0; k < 4; ++k) {
        int i = tid + k * 256;               // 1024 = 32x32
        int o = i >> 5, kk = i & 31;
        whx[o][kk] = (kk < 10) ? f2bf(Wh[o * 10 + kk]) : (unsigned short)0;
    }
    __syncthreads();

    int lane = tid & 63, w = __builtin_amdgcn_readfirstlane(tid >> 6);
    int r16 = lane & 15, g = lane >> 4;
    int bsub = w >> 1, tq = w & 1;
    int bglob = b0 + bsub * 16 + r16;

    // B-operand X frags (j=b on r16), identical k-map as A (permutation-safe)
    bf16x8 xf[4];
#pragma unroll
    for (int s = 0; s < 4; ++s)
        xf[s] = *reinterpret_cast<const bf16x8*>(&xs[bsub * 16 + r16][s * 32 + g * 8]);

    // A-operand weight frags, loaded once
    bf16x8 w1f = *reinterpret_cast<const bf16x8*>(&w1x[r16][g * 8]);
    bf16x8 w2f = *reinterpret_cast<const bf16x8*>(&w2x[r16][g * 8]);
    bf16x8 w3f = *reinterpret_cast<const bf16x8*>(&w3x[r16][g * 8]);
    bf16x8 whAf = *reinterpret_cast<const bf16x8*>(&whx[r16][g * 8]);
    bf16x8 whBf = *reinterpret_cast<const bf16x8*>(&whx[16 + r16][g * 8]);
    f32x4 bhA, bhB;
#pragma unroll
    for (int r = 0; r < 4; ++r) { bhA[r] = bh[g * 4 + r]; bhB[r] = bh[16 + g * 4 + r]; }
    const f32x4 zero4 = {0.f, 0.f, 0.f, 0.f};

    float ce_local = 0.f;

    for (int tt2 = 0; tt2 < 2; ++tt2) {      // runtime outer, unrolled inner (rule #20)
#pragma unroll
        for (int q = 0; q < 4; ++q) {
            int tloc = tq * 8 + tt2 * 4 + q;           // 0..15 within half
            int t = thalf * 16 + tloc;
            // L0: D0[o][b], two independent accumulators to halve the dep chain
            const bf16x8* ap = reinterpret_cast<const bf16x8*>(
                a0p + ((size_t)t * 16 + r16) * 128);
            f32x4 accA = zero4, accB = zero4;
            accA = mfma32(ap[0 * 4 + g], xf[0], accA);
            accB = mfma32(ap[1 * 4 + g], xf[1], accB);
            accA = mfma32(ap[2 * 4 + g], xf[2], accA);
            accB = mfma32(ap[3 * 4 + g], xf[3], accB);
            f32x4 acc;
#pragma unroll
            for (int r = 0; r < 4; ++r) acc[r] = accA[r] + accB[r];

            unsigned p0, p1;
            leaky_pack(acc, p0, p1);
            bf16x8 bf = build_bfrag(p0, p1, g, r16);
            f32x4 d1 = mfma32(w1f, bf, zero4);
            leaky_pack(d1, p0, p1);
            bf = build_bfrag(p0, p1, g, r16);
            f32x4 d2 = mfma32(w2f, bf, zero4);
            leaky_pack(d2, p0, p1);
            bf = build_bfrag(p0, p1, g, r16);
            f32x4 d3 = mfma32(w3f, bf, zero4);   // rep[o=g*4+r][b=r16], o>=10 exact 0

            // rep store (own b row, 10 floats across g=0..2)
            float* rp = rep + (size_t)bglob * CDIM + t * HDIM + g * 4;
            if (g < 2) {
                float2 v0; v0.x = d3[0]; v0.y = d3[1];
                float2 v1; v1.x = d3[2]; v1.y = d3[3];
                reinterpret_cast<float2*>(rp)[0] = v0;
                reinterpret_cast<float2*>(rp)[1] = v1;
            } else if (g == 2) {
                float2 v0; v0.x = d3[0]; v0.y = d3[1];
                reinterpret_cast<float2*>(rp)[0] = v0;
            }

            // mean partial: butterfly over 16 b-lanes
            float m0 = d3[0], m1 = d3[1], m2 = d3[2], m3 = d3[3];
#pragma unroll
            for (int msk = 1; msk < 16; msk <<= 1) {
                m0 += __shfl_xor(m0, msk, 64);
                m1 += __shfl_xor(m1, msk, 64);
                m2 += __shfl_xor(m2, msk, 64);
                m3 += __shfl_xor(m3, msk, 64);
            }
            if (r16 == 0 && g < 3) {
                float4 mv; mv.x = m0; mv.y = m1; mv.z = m2; mv.w = m3;
                *reinterpret_cast<float4*>(&mred[bsub][tloc][g * 4]) = mv;
            }

            // head: pred[o][b] = Wh . leaky(rep) + bh  (2x 16x16x32)
            leaky_pack(d3, p0, p1);
            bf = build_bfrag(p0, p1, g, r16);
            f32x4 pA = mfma32(whAf, bf, bhA);
            f32x4 pB = mfma32(whBf, bf, bhB);

            // LSE over 32 classes (8 in-lane + butterfly over g)
            float mx = fmaxf(fmaxf(fmaxf(pA[0], pA[1]), fmaxf(pA[2], pA[3])),
                             fmaxf(fmaxf(pB[0], pB[1]), fmaxf(pB[2], pB[3])));
            mx = fmaxf(mx, __shfl_xor(mx, 16, 64));
            mx = fmaxf(mx, __shfl_xor(mx, 32, 64));
            float se = __expf(pA[0] - mx) + __expf(pA[1] - mx) +
                       __expf(pA[2] - mx) + __expf(pA[3] - mx) +
                       __expf(pB[0] - mx) + __expf(pB[1] - mx) +
                       __expf(pB[2] - mx) + __expf(pB[3] - mx);
            se += __shfl_xor(se, 16, 64);
            se += __shfl_xor(se, 32, 64);
            float lse = mx + __logf(se);
            // pt = pred[class=t][b=r16]: holder lane g' = tloc>>2 = tq*2 + tt2,
            // reg = q; half picked by thalf (pA: 0..15, pB: 16..31).
            float pr = thalf ? pB[q] : pA[q];
            float ptv = __shfl(pr, (tq * 2 + tt2) * 16 + r16, 64);
            ce_local += lse - ptv;
        }
    }

    if (g == 0) atomicAdd(&ce_acc[bglob], ce_local);
    __syncthreads();
    for (int i = tid; i < 16 * HDIM; i += 256) {
        int tloc = i / 10, o = i - tloc * 10;
        atomicAdd(&mean_acc[(thalf * 16 + tloc) * HDIM + o],
                  mred[0][tloc][o] + mred[1][tloc][o]);
    }
}

// Triplet-center hinge: block = 32 b's staged in LDS, thread = (t, 4 b's).
__global__ __launch_bounds__(256) void tc_kernel(const float* __restrict__ rep,
    const float* __restrict__ mean_acc, float* __restrict__ tc_sum)
{
    __shared__ float tile[32][CDIM];     // 40 KB
    __shared__ float mm[CDIM];
    __shared__ float msq[TDIM];
    __shared__ float wpart[4];
    int tid = threadIdx.x;
    int b0 = blockIdx.x * 32;

    for (int i = tid; i < CDIM; i += 256) mm[i] = mean_acc[i] * (1.f / BTOT);
    const float4* src = reinterpret_cast<const float4*>(rep + (size_t)b0 * CDIM);
#pragma unroll
    for (int k = 0; k < 10; ++k) {       // 2560 float4, coalesced
        int idx = tid + k * 256;
        int row = idx / 80, col4 = idx - row * 80;
        *reinterpret_cast<float4*>(&tile[row][col4 * 4]) = src[idx];
    }
    __syncthreads();
    if (tid < TDIM) {
        float s = 0.f;
#pragma unroll
        for (int h = 0; h < HDIM; ++h) { float v = mm[tid * HDIM + h]; s += v * v; }
        msq[tid] = s;
    }
    __syncthreads();

    int t = tid & 31, bg = tid >> 5;
    float rv[4][HDIM], rsq[4];
#pragma unroll
    for (int j = 0; j < 4; ++j) {
        const float* rp = &tile[bg * 4 + j][t * HDIM];
        float s = 0.f;
#pragma unroll
        for (int q = 0; q < 5; ++q) {
            float2 v = reinterpret_cast<const float2*>(rp)[q];
            rv[j][2 * q] = v.x; rv[j][2 * q + 1] = v.y;
            s += v.x * v.x + v.y * v.y;
        }
        rsq[j] = s;
    }
    float pos[4], neg[4];
#pragma unroll
    for (int j = 0; j < 4; ++j) { pos[j] = 0.f; neg[j] = 1e30f; }
#pragma unroll 4
    for (int c = 0; c < TDIM; ++c) {
        float m0[HDIM];
#pragma unroll
        for (int q = 0; q < 5; ++q) {
            float2 v = reinterpret_cast<const float2*>(&mm[c * HDIM])[q];
            m0[2 * q] = v.x; m0[2 * q + 1] = v.y;
        }
        float mq = msq[c];
        bool isT = (c == t);
#pragma unroll
        for (int j = 0; j < 4; ++j) {
            float dot = 0.f;
#pragma unroll
            for (int h = 0; h < HDIM; ++h) dot += rv[j][h] * m0[h];
            float s = rsq[j] - 2.f * dot + mq;
            if (isT) pos[j] = s;
            float s2 = isT ? s + OFFSET_C : s;
            neg[j] = fminf(neg[j], s2);
        }
    }
    float hs = 0.f;
#pragma unroll
    for (int j = 0; j < 4; ++j) hs += fmaxf(pos[j] + MARGIN_C - neg[j], 0.f);
#pragma unroll
    for (int m = 1; m < 64; m <<= 1) hs += __shfl_xor(hs, m, 64);
    int lane = tid & 63, w = tid >> 6;
    if (lane == 0) wpart[w] = hs;
    __syncthreads();
    if (tid == 0) atomicAdd(tc_sum, wpart[0] + wpart[1] + wpart[2] + wpart[3]);
}

__global__ void final_kernel(const float* __restrict__ ce_acc,
                             const float* __restrict__ tc_sum, float* __restrict__ loss)
{
    int b = blockIdx.x * blockDim.x + threadIdx.x;
    if (b < BTOT)
        loss[b] = ALPHA_C * (tc_sum[0] * (1.f / ((float)BTOT * TDIM)))
                + ce_acc[b] * (1.f / TDIM);
}

extern "C" void kernel_launch(void* const* d_in, const int* in_sizes, int n_in,
                              void* d_out, int out_size, void* d_ws, size_t ws_size,
                              hipStream_t stream) {
    const float* X  = (const float*)d_in[0];
    const float* aw = (const float*)d_in[1];
    const float* W0 = (const float*)d_in[2];
    const float* W1 = (const float*)d_in[3];
    const float* W2 = (const float*)d_in[4];
    const float* W3 = (const float*)d_in[5];
    const float* Wh = (const float*)d_in[6];
    const float* bh = (const float*)d_in[7];
    float* ws = (float*)d_ws;
    unsigned short* a0p = (unsigned short*)(ws + WS_A0P);
    float* mean_acc = ws + WS_MEAN;
    float* tc_sum   = ws + WS_TC;
    float* ce_acc   = ws + WS_CE;
    float* out_rep = (float*)d_out;        // [32768][320]
    float* loss = out_rep + (size_t)BTOT * TDIM * HDIM;

    // zero mean_acc + tc pad + ce_acc
    hipMemsetAsync(mean_acc, 0, (384 + BTOT) * sizeof(float), stream);
    prep_kernel<<<256, 256, 0, stream>>>(aw, W0, a0p);
    gemm0_fused<<<2048, 256, 0, stream>>>(X, a0p, W1, W2, W3, Wh, bh,
                                          out_rep, ce_acc, mean_acc);
    tc_kernel<<<BTOT / 32, 256, 0, stream>>>(out_rep, mean_acc, tc_sum);
    final_kernel<<<BTOT / 256, 256, 0, stream>>>(ce_acc, tc_sum, loss);
}